// Round 3
// baseline (1205.004 us; speedup 1.0000x reference)
//
#include <hip/hip_runtime.h>
#include <math.h>

#define S 1024
#define DM 512
#define H 8
#define HD 64
#define NH 8          // n_hashes
#define NB 16         // n_buckets
#define N 8192        // B*H*S
#define SCALE 0.125f  // 1/sqrt(64)

// ---------------- K1: fused dual projection GEMM (qk and v)
// out[n=h*S+s][dd] = (x @ w + b)[s][h*64+dd]
#define GBS 32
#define GBD 128
#define GBK 32
__global__ __launch_bounds__(256) void proj2_kernel(
    const float* __restrict__ x,
    const float* __restrict__ wqk, const float* __restrict__ bqk,
    const float* __restrict__ wv,  const float* __restrict__ bv,
    float* __restrict__ qkf, float* __restrict__ vf) {
  int sb  = blockIdx.x & 31;
  int db  = (blockIdx.x >> 5) & 3;
  int mat = blockIdx.x >> 7;  // 0=qk, 1=v
  const float* w    = mat ? wv  : wqk;
  const float* bias = mat ? bv  : bqk;
  float* dst        = mat ? vf  : qkf;
  int tid = threadIdx.x;
  int tdx = tid & 31;   // 32 groups x 4 d-cols
  int tsy = tid >> 5;   // 8 groups x 4 s-rows

  __shared__ float  xs[GBS][GBK + 1];
  __shared__ float4 ws4[GBK * (GBD / 4)];

  float acc[4][4];
#pragma unroll
  for (int u = 0; u < 4; ++u)
#pragma unroll
    for (int c = 0; c < 4; ++c) acc[u][c] = 0.f;

  for (int kt = 0; kt < DM; kt += GBK) {
    __syncthreads();
    for (int e = tid; e < GBS * GBK; e += 256) {
      int s = e >> 5, k = e & 31;
      xs[s][k] = x[(sb * GBS + s) * DM + kt + k];
    }
    for (int e = tid; e < GBK * (GBD / 4); e += 256) {
      int k = e >> 5, d4 = e & 31;
      ws4[e] = ((const float4*)(w + (size_t)(kt + k) * DM + db * GBD))[d4];
    }
    __syncthreads();
#pragma unroll 8
    for (int kk = 0; kk < GBK; ++kk) {
      float4 b4 = ws4[kk * 32 + tdx];
      float bcol[4] = {b4.x, b4.y, b4.z, b4.w};
#pragma unroll
      for (int u = 0; u < 4; ++u) {
        float a = xs[tsy * 4 + u][kk];
#pragma unroll
        for (int c = 0; c < 4; ++c)
          acc[u][c] = fmaf(a, bcol[c], acc[u][c]);
      }
    }
  }
  int d0 = db * GBD + tdx * 4;
  float4 bb = *(const float4*)(bias + d0);
  float bbv[4] = {bb.x, bb.y, bb.z, bb.w};
  int h = d0 >> 6, dd = d0 & 63;
#pragma unroll
  for (int u = 0; u < 4; ++u) {
    int s = sb * GBS + tsy * 4 + u;
    float4 o = make_float4(acc[u][0] + bbv[0], acc[u][1] + bbv[1],
                           acc[u][2] + bbv[2], acc[u][3] + bbv[3]);
    *(float4*)(dst + ((size_t)h * S + s) * HD + dd) = o;
  }
}

// ---------------- K2: LSH buckets + histogram
__global__ void bucket_kernel(const float* __restrict__ qkf,
                              const float* __restrict__ rot,
                              int* __restrict__ buckets,
                              int* __restrict__ counts) {
  int g = blockIdx.x * blockDim.x + threadIdx.x;  // 0..65535
  int n = g & (N - 1);
  int r = g >> 13;
  int h = n >> 10;
  const float4* q4 = (const float4*)(qkf + (size_t)n * HD);
  const float* R = rot + (size_t)((r * H + h) * HD) * 8;  // [d][c]
  float v[8];
#pragma unroll
  for (int c = 0; c < 8; ++c) v[c] = 0.f;
  for (int d4 = 0; d4 < 16; ++d4) {
    float4 q = q4[d4];
    const float* Rr = R + d4 * 32;
#pragma unroll
    for (int c = 0; c < 8; ++c) v[c] = fmaf(q.x, Rr[c], v[c]);
#pragma unroll
    for (int c = 0; c < 8; ++c) v[c] = fmaf(q.y, Rr[8 + c], v[c]);
#pragma unroll
    for (int c = 0; c < 8; ++c) v[c] = fmaf(q.z, Rr[16 + c], v[c]);
#pragma unroll
    for (int c = 0; c < 8; ++c) v[c] = fmaf(q.w, Rr[24 + c], v[c]);
  }
  float best = v[0];
  int bi = 0;
#pragma unroll
  for (int c = 1; c < 16; ++c) {
    float val = (c < 8) ? v[c] : -v[c - 8];
    if (val > best) { best = val; bi = c; }
  }
  buckets[r * N + n] = bi;
  atomicAdd(&counts[r * NB + bi], 1);
}

// ---------------- K3: tiny exclusive scan (128 entries)
__global__ void scan_kernel(const int* __restrict__ counts,
                            int* __restrict__ offsets,
                            int* __restrict__ cursor) {
  int t = threadIdx.x;  // 0..127
  int r = t >> 4, b = t & 15;
  int off = r * N;
  for (int i = 0; i < b; ++i) off += counts[r * NB + i];
  offsets[t] = off;
  cursor[t] = off;
}

// ---------------- K4: scatter rows into bucket-sorted order
__global__ void scatter_kernel(const int* __restrict__ buckets,
                               int* __restrict__ cursor,
                               int* __restrict__ perm) {
  int g = blockIdx.x * blockDim.x + threadIdx.x;
  int n = g & (N - 1);
  int r = g >> 13;
  int b = buckets[r * N + n];
  int pos = atomicAdd(&cursor[r * NB + b], 1);
  perm[pos] = n;
}

// ---------------- K5: attention over sorted positions, online softmax
// Block g handles 256 consecutive sorted positions of round r. Sorted order
// means bucket ids are nondecreasing along positions, so thread 0's start and
// thread 255's end bound the block's key range.
#define TILE 64
__global__ __launch_bounds__(256) void attn_kernel(
    const float* __restrict__ qkf, const float* __restrict__ vf,
    const int* __restrict__ perm, const int* __restrict__ buckets,
    const int* __restrict__ offsets, const int* __restrict__ counts,
    float* __restrict__ accum) {
  int r = blockIdx.x >> 5;
  int pb = blockIdx.x & 31;
  int tid = threadIdx.x;
  int p = r * N + pb * 256 + tid;  // global sorted position
  int i = perm[p];
  int b = buckets[r * N + i];
  int start = offsets[r * NB + b];           // includes r*N base
  int end = start + counts[r * NB + b];

  __shared__ int sse[2];
  __shared__ float4 kt4[TILE * 16];
  __shared__ float4 vt4[TILE * 16];
  if (tid == 0) sse[0] = start;
  if (tid == 255) sse[1] = end;
  __syncthreads();
  int bs = sse[0], be = sse[1];

  float4 qi[16], acc[16];
  const float4* qp = (const float4*)(qkf + (size_t)i * HD);
#pragma unroll
  for (int d = 0; d < 16; ++d) {
    float4 q = qp[d];
    qi[d] = make_float4(q.x * SCALE, q.y * SCALE, q.z * SCALE, q.w * SCALE);
    acc[d] = make_float4(0.f, 0.f, 0.f, 0.f);
  }
  float m = -INFINITY, l = 0.f;

  for (int jt = bs; jt < be; jt += TILE) {
    int nj = min(TILE, be - jt);
    __syncthreads();
    for (int e = tid; e < nj * 16; e += 256) {
      int jj = e >> 4, d4 = e & 15;
      int j = perm[jt + jj];
      kt4[e] = ((const float4*)(qkf + (size_t)j * HD))[d4];
      vt4[e] = ((const float4*)(vf + (size_t)j * HD))[d4];
    }
    __syncthreads();
    int lo = max(start - jt, 0);
    int hi = min(end - jt, nj);
    for (int jj = lo; jj < hi; ++jj) {
      const float4* kr = &kt4[jj * 16];
      float4 s4 = make_float4(0.f, 0.f, 0.f, 0.f);
#pragma unroll
      for (int d = 0; d < 16; ++d) {
        float4 k4 = kr[d], q4 = qi[d];
        s4.x = fmaf(q4.x, k4.x, s4.x);
        s4.y = fmaf(q4.y, k4.y, s4.y);
        s4.z = fmaf(q4.z, k4.z, s4.z);
        s4.w = fmaf(q4.w, k4.w, s4.w);
      }
      float sdot = (s4.x + s4.y) + (s4.z + s4.w);
      const float4* vr = &vt4[jj * 16];
      if (sdot <= m) {            // common fast path: no rescale
        float pw = __expf(sdot - m);
        l += pw;
#pragma unroll
        for (int d = 0; d < 16; ++d) {
          float4 v4 = vr[d];
          acc[d].x = fmaf(pw, v4.x, acc[d].x);
          acc[d].y = fmaf(pw, v4.y, acc[d].y);
          acc[d].z = fmaf(pw, v4.z, acc[d].z);
          acc[d].w = fmaf(pw, v4.w, acc[d].w);
        }
      } else {                    // rare: new max, rescale (pw == 1)
        float corr = __expf(m - sdot);  // exp(-inf)=0 handles first key
        m = sdot;
        l = fmaf(l, corr, 1.f);
#pragma unroll
        for (int d = 0; d < 16; ++d) {
          float4 v4 = vr[d];
          acc[d].x = fmaf(acc[d].x, corr, v4.x);
          acc[d].y = fmaf(acc[d].y, corr, v4.y);
          acc[d].z = fmaf(acc[d].z, corr, v4.z);
          acc[d].w = fmaf(acc[d].w, corr, v4.w);
        }
      }
    }
  }
  float inv = 1.f / l;
  float* dst = accum + (size_t)i * HD;
#pragma unroll
  for (int d = 0; d < 16; ++d) {
    atomicAdd(dst + d * 4 + 0, acc[d].x * inv);
    atomicAdd(dst + d * 4 + 1, acc[d].y * inv);
    atomicAdd(dst + d * 4 + 2, acc[d].z * inv);
    atomicAdd(dst + d * 4 + 3, acc[d].w * inv);
  }
}

// ---------------- K6: output projection (register-tiled GEMM)
__global__ __launch_bounds__(256) void outproj_kernel(
    const float* __restrict__ accum, const float* __restrict__ w_o,
    const float* __restrict__ b_o, float* __restrict__ out) {
  int sb = blockIdx.x & 31;
  int db = blockIdx.x >> 5;  // 0..3
  int tid = threadIdx.x;
  int tdx = tid & 31;
  int tsy = tid >> 5;

  __shared__ float  xs[GBS][GBK + 1];
  __shared__ float4 ws4[GBK * (GBD / 4)];

  float acc[4][4];
#pragma unroll
  for (int u = 0; u < 4; ++u)
#pragma unroll
    for (int c = 0; c < 4; ++c) acc[u][c] = 0.f;

  for (int kt = 0; kt < DM; kt += GBK) {
    __syncthreads();
    for (int e = tid; e < GBS * GBK; e += 256) {
      int s = e >> 5, k = e & 31;
      int kg = kt + k;
      int h = kg >> 6, dd = kg & 63;
      xs[s][k] = accum[((size_t)h * S + sb * GBS + s) * HD + dd] * 0.125f;
    }
    for (int e = tid; e < GBK * (GBD / 4); e += 256) {
      int k = e >> 5, d4 = e & 31;
      ws4[e] = ((const float4*)(w_o + (size_t)(kt + k) * DM + db * GBD))[d4];
    }
    __syncthreads();
#pragma unroll 8
    for (int kk = 0; kk < GBK; ++kk) {
      float4 b4 = ws4[kk * 32 + tdx];
      float bcol[4] = {b4.x, b4.y, b4.z, b4.w};
#pragma unroll
      for (int u = 0; u < 4; ++u) {
        float a = xs[tsy * 4 + u][kk];
#pragma unroll
        for (int c = 0; c < 4; ++c)
          acc[u][c] = fmaf(a, bcol[c], acc[u][c]);
      }
    }
  }
  int d0 = db * GBD + tdx * 4;
  float4 bb = *(const float4*)(b_o + d0);
  float bbv[4] = {bb.x, bb.y, bb.z, bb.w};
#pragma unroll
  for (int u = 0; u < 4; ++u) {
    int s = sb * GBS + tsy * 4 + u;
    float4 o = make_float4(acc[u][0] + bbv[0], acc[u][1] + bbv[1],
                           acc[u][2] + bbv[2], acc[u][3] + bbv[3]);
    *(float4*)(out + (size_t)s * DM + d0) = o;
  }
}

extern "C" void kernel_launch(void* const* d_in, const int* in_sizes, int n_in,
                              void* d_out, int out_size, void* d_ws, size_t ws_size,
                              hipStream_t stream) {
  const float* x    = (const float*)d_in[0];
  const float* w_qk = (const float*)d_in[1];
  const float* b_qk = (const float*)d_in[2];
  const float* w_v  = (const float*)d_in[3];
  const float* b_v  = (const float*)d_in[4];
  const float* w_o  = (const float*)d_in[5];
  const float* b_o  = (const float*)d_in[6];
  const float* rot  = (const float*)d_in[7];
  float* out = (float*)d_out;

  char* ws = (char*)d_ws;
  float* qkf   = (float*)(ws);                        // 2 MB
  float* vf    = (float*)(ws + 2u * 1024 * 1024);     // 2 MB
  float* accum = (float*)(ws + 4u * 1024 * 1024);     // 2 MB
  int* buckets = (int*)(ws + 6u * 1024 * 1024);       // 256 KB
  int* perm    = (int*)(ws + 6u * 1024 * 1024 + 256u * 1024);  // 256 KB
  int* counts  = (int*)(ws + 6u * 1024 * 1024 + 512u * 1024);  // 512 B
  int* offsets = counts + 128;
  int* cursor  = offsets + 128;

  hipMemsetAsync(counts, 0, 128 * sizeof(int), stream);
  hipMemsetAsync(accum, 0, (size_t)N * HD * sizeof(float), stream);

  proj2_kernel<<<256, 256, 0, stream>>>(x, w_qk, b_qk, w_v, b_v, qkf, vf);
  bucket_kernel<<<(NH * N) / 256, 256, 0, stream>>>(qkf, rot, buckets, counts);
  scan_kernel<<<1, 128, 0, stream>>>(counts, offsets, cursor);
  scatter_kernel<<<(NH * N) / 256, 256, 0, stream>>>(buckets, cursor, perm);
  attn_kernel<<<NH * 32, 256, 0, stream>>>(qkf, vf, perm, buckets, offsets, counts, accum);
  outproj_kernel<<<128, 256, 0, stream>>>(accum, w_o, b_o, out);
}

// Round 4
// 785.968 us; speedup vs baseline: 1.5331x; 1.5331x over previous
//
#include <hip/hip_runtime.h>
#include <math.h>

#define S 1024
#define DM 512
#define H 8
#define HD 64
#define NH 8          // n_hashes
#define NB 16         // n_buckets
#define N 8192        // B*H*S
#define SCALE 0.125f  // 1/sqrt(64)

// ---------------- K1: fused dual projection GEMM (qk and v)
#define GBS 32
#define GBD 128
#define GBK 32
__global__ __launch_bounds__(256) void proj2_kernel(
    const float* __restrict__ x,
    const float* __restrict__ wqk, const float* __restrict__ bqk,
    const float* __restrict__ wv,  const float* __restrict__ bv,
    float* __restrict__ qkf, float* __restrict__ vf) {
  int sb  = blockIdx.x & 31;
  int db  = (blockIdx.x >> 5) & 3;
  int mat = blockIdx.x >> 7;  // 0=qk, 1=v
  const float* w    = mat ? wv  : wqk;
  const float* bias = mat ? bv  : bqk;
  float* dst        = mat ? vf  : qkf;
  int tid = threadIdx.x;
  int tdx = tid & 31;
  int tsy = tid >> 5;

  __shared__ float  xs[GBS][GBK + 1];
  __shared__ float4 ws4[GBK * (GBD / 4)];

  float acc[4][4];
#pragma unroll
  for (int u = 0; u < 4; ++u)
#pragma unroll
    for (int c = 0; c < 4; ++c) acc[u][c] = 0.f;

  for (int kt = 0; kt < DM; kt += GBK) {
    __syncthreads();
    for (int e = tid; e < GBS * GBK; e += 256) {
      int s = e >> 5, k = e & 31;
      xs[s][k] = x[(sb * GBS + s) * DM + kt + k];
    }
    for (int e = tid; e < GBK * (GBD / 4); e += 256) {
      int k = e >> 5, d4 = e & 31;
      ws4[e] = ((const float4*)(w + (size_t)(kt + k) * DM + db * GBD))[d4];
    }
    __syncthreads();
#pragma unroll 8
    for (int kk = 0; kk < GBK; ++kk) {
      float4 b4 = ws4[kk * 32 + tdx];
      float bcol[4] = {b4.x, b4.y, b4.z, b4.w};
#pragma unroll
      for (int u = 0; u < 4; ++u) {
        float a = xs[tsy * 4 + u][kk];
#pragma unroll
        for (int c = 0; c < 4; ++c)
          acc[u][c] = fmaf(a, bcol[c], acc[u][c]);
      }
    }
  }
  int d0 = db * GBD + tdx * 4;
  float4 bb = *(const float4*)(bias + d0);
  float bbv[4] = {bb.x, bb.y, bb.z, bb.w};
  int h = d0 >> 6, dd = d0 & 63;
#pragma unroll
  for (int u = 0; u < 4; ++u) {
    int s = sb * GBS + tsy * 4 + u;
    float4 o = make_float4(acc[u][0] + bbv[0], acc[u][1] + bbv[1],
                           acc[u][2] + bbv[2], acc[u][3] + bbv[3]);
    *(float4*)(dst + ((size_t)h * S + s) * HD + dd) = o;
  }
}

// ---------------- K2: LSH buckets + histogram
__global__ void bucket_kernel(const float* __restrict__ qkf,
                              const float* __restrict__ rot,
                              int* __restrict__ buckets,
                              int* __restrict__ counts) {
  int g = blockIdx.x * blockDim.x + threadIdx.x;
  int n = g & (N - 1);
  int r = g >> 13;
  int h = n >> 10;
  const float4* q4 = (const float4*)(qkf + (size_t)n * HD);
  const float* R = rot + (size_t)((r * H + h) * HD) * 8;
  float v[8];
#pragma unroll
  for (int c = 0; c < 8; ++c) v[c] = 0.f;
  for (int d4 = 0; d4 < 16; ++d4) {
    float4 q = q4[d4];
    const float* Rr = R + d4 * 32;
#pragma unroll
    for (int c = 0; c < 8; ++c) v[c] = fmaf(q.x, Rr[c], v[c]);
#pragma unroll
    for (int c = 0; c < 8; ++c) v[c] = fmaf(q.y, Rr[8 + c], v[c]);
#pragma unroll
    for (int c = 0; c < 8; ++c) v[c] = fmaf(q.z, Rr[16 + c], v[c]);
#pragma unroll
    for (int c = 0; c < 8; ++c) v[c] = fmaf(q.w, Rr[24 + c], v[c]);
  }
  float best = v[0];
  int bi = 0;
#pragma unroll
  for (int c = 1; c < 16; ++c) {
    float val = (c < 8) ? v[c] : -v[c - 8];
    if (val > best) { best = val; bi = c; }
  }
  buckets[r * N + n] = bi;
  atomicAdd(&counts[r * NB + bi], 1);
}

// ---------------- K3: tiny exclusive scan (128 entries)
__global__ void scan_kernel(const int* __restrict__ counts,
                            int* __restrict__ offsets,
                            int* __restrict__ cursor) {
  int t = threadIdx.x;
  int r = t >> 4, b = t & 15;
  int off = r * N;
  for (int i = 0; i < b; ++i) off += counts[r * NB + i];
  offsets[t] = off;
  cursor[t] = off;
}

// ---------------- K4: scatter rows into bucket-sorted order
__global__ void scatter_kernel(const int* __restrict__ buckets,
                               int* __restrict__ cursor,
                               int* __restrict__ perm) {
  int g = blockIdx.x * blockDim.x + threadIdx.x;
  int n = g & (N - 1);
  int r = g >> 13;
  int b = buckets[r * N + n];
  int pos = atomicAdd(&cursor[r * NB + b], 1);
  perm[pos] = n;
}

// ---------------- K5: attention, 2 threads per query (dim-split),
// online softmax. Block handles 128 consecutive sorted positions.
// Lane pair (2k,2k+1) owns query k: lane parity selects dims [0,32)/[32,64).
// Partial dots combined via __shfl_xor(.,1) — symmetric sum, so the pair's
// m/l/branch state stays bit-identical (no intra-pair divergence).
#define TILE 64
#define QPB 128  // queries per block
__global__ __launch_bounds__(256) void attn_kernel(
    const float* __restrict__ qkf, const float* __restrict__ vf,
    const int* __restrict__ perm, const int* __restrict__ buckets,
    const int* __restrict__ offsets, const int* __restrict__ counts,
    float* __restrict__ accum) {
  int r = blockIdx.x >> 6;
  int pb = blockIdx.x & 63;
  int tid = threadIdx.x;
  int q = tid >> 1;           // 0..127 query slot
  int half = tid & 1;         // dim half
  int p = r * N + pb * QPB + q;
  int i = perm[p];
  int b = buckets[r * N + i];
  int start = offsets[r * NB + b];  // includes r*N base
  int end = start + counts[r * NB + b];

  __shared__ int sse[2];
  __shared__ float4 kt4[TILE * 16];
  __shared__ float4 vt4[TILE * 16];
  if (tid == 0) sse[0] = start;
  if (tid == 255) sse[1] = end;
  __syncthreads();
  int bs = sse[0], be = sse[1];

  float4 qi[8], acc[8];
  const float4* qp = (const float4*)(qkf + (size_t)i * HD) + half * 8;
#pragma unroll
  for (int d = 0; d < 8; ++d) {
    float4 qv = qp[d];
    qi[d] = make_float4(qv.x * SCALE, qv.y * SCALE, qv.z * SCALE, qv.w * SCALE);
    acc[d] = make_float4(0.f, 0.f, 0.f, 0.f);
  }
  float m = -INFINITY, l = 0.f;

  for (int jt = bs; jt < be; jt += TILE) {
    int nj = min(TILE, be - jt);
    __syncthreads();
    for (int e = tid; e < nj * 16; e += 256) {
      int jj = e >> 4, d4 = e & 15;
      int j = perm[jt + jj];
      kt4[e] = ((const float4*)(qkf + (size_t)j * HD))[d4];
      vt4[e] = ((const float4*)(vf + (size_t)j * HD))[d4];
    }
    __syncthreads();
    int lo = max(start - jt, 0);
    int hi = min(end - jt, nj);
    for (int jj = lo; jj < hi; ++jj) {
      const float4* kr = &kt4[jj * 16 + half * 8];
      float4 s4 = make_float4(0.f, 0.f, 0.f, 0.f);
#pragma unroll
      for (int d = 0; d < 8; ++d) {
        float4 k4 = kr[d], q4 = qi[d];
        s4.x = fmaf(q4.x, k4.x, s4.x);
        s4.y = fmaf(q4.y, k4.y, s4.y);
        s4.z = fmaf(q4.z, k4.z, s4.z);
        s4.w = fmaf(q4.w, k4.w, s4.w);
      }
      float part = (s4.x + s4.y) + (s4.z + s4.w);
      float sdot = part + __shfl_xor(part, 1);
      const float4* vr = &vt4[jj * 16 + half * 8];
      if (sdot <= m) {            // common fast path: no rescale
        float pw = __expf(sdot - m);
        l += pw;
#pragma unroll
        for (int d = 0; d < 8; ++d) {
          float4 v4 = vr[d];
          acc[d].x = fmaf(pw, v4.x, acc[d].x);
          acc[d].y = fmaf(pw, v4.y, acc[d].y);
          acc[d].z = fmaf(pw, v4.z, acc[d].z);
          acc[d].w = fmaf(pw, v4.w, acc[d].w);
        }
      } else {                    // rare: new max, rescale (pw == 1)
        float corr = __expf(m - sdot);  // exp(-inf)=0 handles first key
        m = sdot;
        l = fmaf(l, corr, 1.f);
#pragma unroll
        for (int d = 0; d < 8; ++d) {
          float4 v4 = vr[d];
          acc[d].x = fmaf(acc[d].x, corr, v4.x);
          acc[d].y = fmaf(acc[d].y, corr, v4.y);
          acc[d].z = fmaf(acc[d].z, corr, v4.z);
          acc[d].w = fmaf(acc[d].w, corr, v4.w);
        }
      }
    }
  }
  float inv = 1.f / l;
  float* dst = accum + (size_t)i * HD + half * 32;
#pragma unroll
  for (int d = 0; d < 8; ++d) {
    atomicAdd(dst + d * 4 + 0, acc[d].x * inv);
    atomicAdd(dst + d * 4 + 1, acc[d].y * inv);
    atomicAdd(dst + d * 4 + 2, acc[d].z * inv);
    atomicAdd(dst + d * 4 + 3, acc[d].w * inv);
  }
}

// ---------------- K6: output projection (register-tiled GEMM)
__global__ __launch_bounds__(256) void outproj_kernel(
    const float* __restrict__ accum, const float* __restrict__ w_o,
    const float* __restrict__ b_o, float* __restrict__ out) {
  int sb = blockIdx.x & 31;
  int db = blockIdx.x >> 5;
  int tid = threadIdx.x;
  int tdx = tid & 31;
  int tsy = tid >> 5;

  __shared__ float  xs[GBS][GBK + 1];
  __shared__ float4 ws4[GBK * (GBD / 4)];

  float acc[4][4];
#pragma unroll
  for (int u = 0; u < 4; ++u)
#pragma unroll
    for (int c = 0; c < 4; ++c) acc[u][c] = 0.f;

  for (int kt = 0; kt < DM; kt += GBK) {
    __syncthreads();
    for (int e = tid; e < GBS * GBK; e += 256) {
      int s = e >> 5, k = e & 31;
      int kg = kt + k;
      int h = kg >> 6, dd = kg & 63;
      xs[s][k] = accum[((size_t)h * S + sb * GBS + s) * HD + dd] * 0.125f;
    }
    for (int e = tid; e < GBK * (GBD / 4); e += 256) {
      int k = e >> 5, d4 = e & 31;
      ws4[e] = ((const float4*)(w_o + (size_t)(kt + k) * DM + db * GBD))[d4];
    }
    __syncthreads();
#pragma unroll 8
    for (int kk = 0; kk < GBK; ++kk) {
      float4 b4 = ws4[kk * 32 + tdx];
      float bcol[4] = {b4.x, b4.y, b4.z, b4.w};
#pragma unroll
      for (int u = 0; u < 4; ++u) {
        float a = xs[tsy * 4 + u][kk];
#pragma unroll
        for (int c = 0; c < 4; ++c)
          acc[u][c] = fmaf(a, bcol[c], acc[u][c]);
      }
    }
  }
  int d0 = db * GBD + tdx * 4;
  float4 bb = *(const float4*)(b_o + d0);
  float bbv[4] = {bb.x, bb.y, bb.z, bb.w};
#pragma unroll
  for (int u = 0; u < 4; ++u) {
    int s = sb * GBS + tsy * 4 + u;
    float4 o = make_float4(acc[u][0] + bbv[0], acc[u][1] + bbv[1],
                           acc[u][2] + bbv[2], acc[u][3] + bbv[3]);
    *(float4*)(out + (size_t)s * DM + d0) = o;
  }
}

extern "C" void kernel_launch(void* const* d_in, const int* in_sizes, int n_in,
                              void* d_out, int out_size, void* d_ws, size_t ws_size,
                              hipStream_t stream) {
  const float* x    = (const float*)d_in[0];
  const float* w_qk = (const float*)d_in[1];
  const float* b_qk = (const float*)d_in[2];
  const float* w_v  = (const float*)d_in[3];
  const float* b_v  = (const float*)d_in[4];
  const float* w_o  = (const float*)d_in[5];
  const float* b_o  = (const float*)d_in[6];
  const float* rot  = (const float*)d_in[7];
  float* out = (float*)d_out;

  char* ws = (char*)d_ws;
  float* qkf   = (float*)(ws);                        // 2 MB
  float* vf    = (float*)(ws + 2u * 1024 * 1024);     // 2 MB
  float* accum = (float*)(ws + 4u * 1024 * 1024);     // 2 MB
  int* buckets = (int*)(ws + 6u * 1024 * 1024);       // 256 KB
  int* perm    = (int*)(ws + 6u * 1024 * 1024 + 256u * 1024);  // 256 KB
  int* counts  = (int*)(ws + 6u * 1024 * 1024 + 512u * 1024);  // 512 B
  int* offsets = counts + 128;
  int* cursor  = offsets + 128;

  hipMemsetAsync(counts, 0, 128 * sizeof(int), stream);
  hipMemsetAsync(accum, 0, (size_t)N * HD * sizeof(float), stream);

  proj2_kernel<<<256, 256, 0, stream>>>(x, w_qk, b_qk, w_v, b_v, qkf, vf);
  bucket_kernel<<<(NH * N) / 256, 256, 0, stream>>>(qkf, rot, buckets, counts);
  scan_kernel<<<1, 128, 0, stream>>>(counts, offsets, cursor);
  scatter_kernel<<<(NH * N) / 256, 256, 0, stream>>>(buckets, cursor, perm);
  attn_kernel<<<NH * 64, 256, 0, stream>>>(qkf, vf, perm, buckets, offsets, counts, accum);
  outproj_kernel<<<128, 256, 0, stream>>>(accum, w_o, b_o, out);
}

// Round 5
// 371.992 us; speedup vs baseline: 3.2393x; 2.1129x over previous
//
#include <hip/hip_runtime.h>
#include <math.h>

#define S 1024
#define DM 512
#define H 8
#define HD 64
#define NH 8          // n_hashes
#define NB 16         // n_buckets
#define N 8192        // B*H*S
#define SCALE 0.125f  // 1/sqrt(64)

typedef __attribute__((ext_vector_type(4))) float f32x4;
typedef __attribute__((ext_vector_type(8))) short s16x8;
typedef __attribute__((ext_vector_type(4))) short s16x4;

__device__ __forceinline__ short f2bf(float f) {  // RTNE float->bf16
  union { float f; unsigned u; } a; a.f = f;
  unsigned r = a.u + 0x7fffu + ((a.u >> 16) & 1u);
  return (short)(r >> 16);
}

#if __has_builtin(__builtin_amdgcn_mfma_f32_16x16x16_bf16)
#define MFMA_PV(a, b, c) __builtin_amdgcn_mfma_f32_16x16x16_bf16(a, b, c, 0, 0, 0)
#else
#define MFMA_PV(a, b, c) __builtin_amdgcn_mfma_f32_16x16x16bf16_1k(a, b, c, 0, 0, 0)
#endif

// ---------------- K1: fused dual projection GEMM (qk and v)
#define GBS 32
#define GBD 128
#define GBK 32
__global__ __launch_bounds__(256) void proj2_kernel(
    const float* __restrict__ x,
    const float* __restrict__ wqk, const float* __restrict__ bqk,
    const float* __restrict__ wv,  const float* __restrict__ bv,
    float* __restrict__ qkf, float* __restrict__ vf) {
  int sb  = blockIdx.x & 31;
  int db  = (blockIdx.x >> 5) & 3;
  int mat = blockIdx.x >> 7;  // 0=qk, 1=v
  const float* w    = mat ? wv  : wqk;
  const float* bias = mat ? bv  : bqk;
  float* dst        = mat ? vf  : qkf;
  int tid = threadIdx.x;
  int tdx = tid & 31;
  int tsy = tid >> 5;

  __shared__ float  xs[GBS][GBK + 1];
  __shared__ float4 ws4[GBK * (GBD / 4)];

  float acc[4][4];
#pragma unroll
  for (int u = 0; u < 4; ++u)
#pragma unroll
    for (int c = 0; c < 4; ++c) acc[u][c] = 0.f;

  for (int kt = 0; kt < DM; kt += GBK) {
    __syncthreads();
    for (int e = tid; e < GBS * GBK; e += 256) {
      int s = e >> 5, k = e & 31;
      xs[s][k] = x[(sb * GBS + s) * DM + kt + k];
    }
    for (int e = tid; e < GBK * (GBD / 4); e += 256) {
      int k = e >> 5, d4 = e & 31;
      ws4[e] = ((const float4*)(w + (size_t)(kt + k) * DM + db * GBD))[d4];
    }
    __syncthreads();
#pragma unroll 8
    for (int kk = 0; kk < GBK; ++kk) {
      float4 b4 = ws4[kk * 32 + tdx];
      float bcol[4] = {b4.x, b4.y, b4.z, b4.w};
#pragma unroll
      for (int u = 0; u < 4; ++u) {
        float a = xs[tsy * 4 + u][kk];
#pragma unroll
        for (int c = 0; c < 4; ++c)
          acc[u][c] = fmaf(a, bcol[c], acc[u][c]);
      }
    }
  }
  int d0 = db * GBD + tdx * 4;
  float4 bb = *(const float4*)(bias + d0);
  float bbv[4] = {bb.x, bb.y, bb.z, bb.w};
  int h = d0 >> 6, dd = d0 & 63;
#pragma unroll
  for (int u = 0; u < 4; ++u) {
    int s = sb * GBS + tsy * 4 + u;
    float4 o = make_float4(acc[u][0] + bbv[0], acc[u][1] + bbv[1],
                           acc[u][2] + bbv[2], acc[u][3] + bbv[3]);
    *(float4*)(dst + ((size_t)h * S + s) * HD + dd) = o;
  }
}

// ---------------- K2: LSH buckets + histogram
__global__ void bucket_kernel(const float* __restrict__ qkf,
                              const float* __restrict__ rot,
                              int* __restrict__ buckets,
                              int* __restrict__ counts) {
  int g = blockIdx.x * blockDim.x + threadIdx.x;
  int n = g & (N - 1);
  int r = g >> 13;
  int h = n >> 10;
  const float4* q4 = (const float4*)(qkf + (size_t)n * HD);
  const float* R = rot + (size_t)((r * H + h) * HD) * 8;
  float v[8];
#pragma unroll
  for (int c = 0; c < 8; ++c) v[c] = 0.f;
  for (int d4 = 0; d4 < 16; ++d4) {
    float4 q = q4[d4];
    const float* Rr = R + d4 * 32;
#pragma unroll
    for (int c = 0; c < 8; ++c) v[c] = fmaf(q.x, Rr[c], v[c]);
#pragma unroll
    for (int c = 0; c < 8; ++c) v[c] = fmaf(q.y, Rr[8 + c], v[c]);
#pragma unroll
    for (int c = 0; c < 8; ++c) v[c] = fmaf(q.z, Rr[16 + c], v[c]);
#pragma unroll
    for (int c = 0; c < 8; ++c) v[c] = fmaf(q.w, Rr[24 + c], v[c]);
  }
  float best = v[0];
  int bi = 0;
#pragma unroll
  for (int c = 1; c < 16; ++c) {
    float val = (c < 8) ? v[c] : -v[c - 8];
    if (val > best) { best = val; bi = c; }
  }
  buckets[r * N + n] = bi;
  atomicAdd(&counts[r * NB + bi], 1);
}

// ---------------- K3: tiny exclusive scan (128 entries)
__global__ void scan_kernel(const int* __restrict__ counts,
                            int* __restrict__ offsets,
                            int* __restrict__ cursor) {
  int t = threadIdx.x;
  int r = t >> 4, b = t & 15;
  int off = r * N;
  for (int i = 0; i < b; ++i) off += counts[r * NB + i];
  offsets[t] = off;
  cursor[t] = off;
}

// ---------------- K4: scatter rows into bucket-sorted order
__global__ void scatter_kernel(const int* __restrict__ buckets,
                               int* __restrict__ cursor,
                               int* __restrict__ perm) {
  int g = blockIdx.x * blockDim.x + threadIdx.x;
  int n = g & (N - 1);
  int r = g >> 13;
  int b = buckets[r * N + n];
  int pos = atomicAdd(&cursor[r * NB + b], 1);
  perm[pos] = n;
}

// ---------------- K5: MFMA flash attention over sorted positions.
// Block = 4 waves = 64 consecutive sorted positions of round r; wave owns 16.
// S^T = K_tile x Q^T via mfma_f32_16x16x32_bf16 (C: col=query, row=key);
// that C-layout IS the B-operand layout for K=16 MFMA, so
// O^T += V^T x P^T via mfma_f32_16x16x16_bf16 with no transpose.
#define KT 64
#define KST 72   // shorts per K row (64 + 8 pad, swizzled 16-chunks)
#define VST 66   // shorts per V^T row (64 keys + 2 pad, swizzled 4-groups)
__global__ __launch_bounds__(256) void attn_kernel(
    const float* __restrict__ qkf, const float* __restrict__ vf,
    const int* __restrict__ perm, const int* __restrict__ buckets,
    const int* __restrict__ offsets, const int* __restrict__ counts,
    float* __restrict__ accum) {
  int r = blockIdx.x >> 7;
  int pb = blockIdx.x & 127;
  int tid = threadIdx.x;
  int wave = tid >> 6, lane = tid & 63;
  int col = lane & 15, quad = lane >> 4;

  __shared__ short k_lds[KT * KST];
  __shared__ short v_lds[HD * VST];
  __shared__ int sse[2];

  int p = r * N + (pb << 6) + (wave << 4) + col;   // my query (column)
  int qidx = perm[p];
  int qb = buckets[r * N + qidx];
  int q_start = offsets[r * NB + qb];   // includes r*N base
  int q_end = q_start + counts[r * NB + qb];

  if (tid == 0) sse[0] = q_start;
  if (tid == 255) sse[1] = q_end;
  for (int e = tid; e < HD * VST / 2; e += 256) ((int*)v_lds)[e] = 0;

  // Q fragments: B[k=dim][col=query], lane holds dims s2*32+quad*8+j (scale folded)
  s16x8 qa[2];
  {
    const float* qp = qkf + (size_t)qidx * HD;
#pragma unroll
    for (int s2 = 0; s2 < 2; ++s2) {
      const float4* q4 = (const float4*)(qp + s2 * 32 + quad * 8);
      float4 u0 = q4[0], u1 = q4[1];
      s16x8 f;
      f[0] = f2bf(u0.x * SCALE); f[1] = f2bf(u0.y * SCALE);
      f[2] = f2bf(u0.z * SCALE); f[3] = f2bf(u0.w * SCALE);
      f[4] = f2bf(u1.x * SCALE); f[5] = f2bf(u1.y * SCALE);
      f[6] = f2bf(u1.z * SCALE); f[7] = f2bf(u1.w * SCALE);
      qa[s2] = f;
    }
  }
  int wbs = __shfl(q_start, 0);    // wave's first query start
  int wbe = __shfl(q_end, 15);     // wave's last query end
  __syncthreads();
  int bs = sse[0], be = sse[1];

  float m_run = -1e30f, l_run = 0.f;
  f32x4 o0 = {0,0,0,0}, o1 = {0,0,0,0}, o2 = {0,0,0,0}, o3 = {0,0,0,0};

  int jsk = tid >> 2, csk = tid & 3;
  for (int jt = bs; jt < be; jt += KT) {
    int nj = min(KT, be - jt);
    __syncthreads();
    if (jsk < nj) {   // stage 64 keys: K[key][dim] swizzled, V^T[dim][key] swizzled
      int g = perm[jt + jsk];
      const float4* kp = (const float4*)(qkf + (size_t)g * HD) + (csk << 2);
      float4 a0 = kp[0], a1 = kp[1], a2 = kp[2], a3 = kp[3];
      s16x8 w0, w1;
      w0[0]=f2bf(a0.x); w0[1]=f2bf(a0.y); w0[2]=f2bf(a0.z); w0[3]=f2bf(a0.w);
      w0[4]=f2bf(a1.x); w0[5]=f2bf(a1.y); w0[6]=f2bf(a1.z); w0[7]=f2bf(a1.w);
      w1[0]=f2bf(a2.x); w1[1]=f2bf(a2.y); w1[2]=f2bf(a2.z); w1[3]=f2bf(a2.w);
      w1[4]=f2bf(a3.x); w1[5]=f2bf(a3.y); w1[6]=f2bf(a3.z); w1[7]=f2bf(a3.w);
      int cs = csk ^ (jsk & 3);
      s16x8* kd = (s16x8*)&k_lds[jsk * KST + (cs << 4)];
      kd[0] = w0; kd[1] = w1;
      const float4* vp = (const float4*)(vf + (size_t)g * HD) + (csk << 2);
      float4 b0 = vp[0], b1 = vp[1], b2 = vp[2], b3 = vp[3];
      float vv[16] = {b0.x,b0.y,b0.z,b0.w, b1.x,b1.y,b1.z,b1.w,
                      b2.x,b2.y,b2.z,b2.w, b3.x,b3.y,b3.z,b3.w};
      int jh = jsk >> 2, jl = jsk & 3;
#pragma unroll
      for (int t = 0; t < 16; ++t) {
        int d = (csk << 4) + t;
        v_lds[d * VST + ((jh ^ (t & 3)) << 2) + jl] = f2bf(vv[t]);
      }
    }
    __syncthreads();
    if (jt >= wbe || jt + KT <= wbs) continue;
    int c_lo = (wbs > jt) ? ((wbs - jt) >> 4) : 0;
    int c_hi = min(4, (wbe - jt + 15) >> 4);
    for (int c16 = c_lo; c16 < c_hi; ++c16) {
      // S^T chunk: A = K (16 keys x 64 dims), B = Q^T
      f32x4 sacc = {0,0,0,0};
      int krow = (c16 << 4) + col;
      const short* kb = &k_lds[krow * KST];
#pragma unroll
      for (int s2 = 0; s2 < 2; ++s2) {
        int cidx = ((s2 << 1) + (quad >> 1)) ^ (krow & 3);
        s16x8 kf = *(const s16x8*)&kb[(cidx << 4) + ((quad & 1) << 3)];
        sacc = __builtin_amdgcn_mfma_f32_16x16x32_bf16(kf, qa[s2], sacc, 0, 0, 0);
      }
      // bucket mask + online softmax (per column = per query)
      int kbase = jt + (c16 << 4) + (quad << 2);
      float sr[4];
#pragma unroll
      for (int u = 0; u < 4; ++u) {
        int pos = kbase + u;
        bool ok = (pos >= q_start) && (pos < q_end);
        sr[u] = ok ? sacc[u] : -INFINITY;
      }
      float cmax = fmaxf(fmaxf(sr[0], sr[1]), fmaxf(sr[2], sr[3]));
      cmax = fmaxf(cmax, __shfl_xor(cmax, 16));
      cmax = fmaxf(cmax, __shfl_xor(cmax, 32));
      float newm = fmaxf(m_run, cmax);
      float corr = __expf(m_run - newm);
      float pw[4];
#pragma unroll
      for (int u = 0; u < 4; ++u) pw[u] = __expf(sr[u] - newm);
      float csum = (pw[0] + pw[1]) + (pw[2] + pw[3]);
      csum += __shfl_xor(csum, 16);
      csum += __shfl_xor(csum, 32);
      l_run = l_run * corr + csum;
      m_run = newm;
      o0 *= corr; o1 *= corr; o2 *= corr; o3 *= corr;
      s16x4 pf;
      pf[0] = f2bf(pw[0]); pf[1] = f2bf(pw[1]);
      pf[2] = f2bf(pw[2]); pf[3] = f2bf(pw[3]);
      // PV: O^T += V^T x P^T (A = V^T chunk, B = P^T already in-layout)
#pragma unroll
      for (int c = 0; c < 4; ++c) {
        int dl = (c << 4) + col;
        int grp = ((c16 << 2) + quad) ^ (col & 3);
        int off = dl * VST + (grp << 2);
        int lo_ = *(const int*)&v_lds[off];
        int hi_ = *(const int*)&v_lds[off + 2];
        s16x4 vfr;
        vfr[0] = (short)(lo_ & 0xffff); vfr[1] = (short)(lo_ >> 16);
        vfr[2] = (short)(hi_ & 0xffff); vfr[3] = (short)(hi_ >> 16);
        if (c == 0) o0 = MFMA_PV(vfr, pf, o0);
        else if (c == 1) o1 = MFMA_PV(vfr, pf, o1);
        else if (c == 2) o2 = MFMA_PV(vfr, pf, o2);
        else o3 = MFMA_PV(vfr, pf, o3);
      }
    }
  }
  float inv = 1.f / l_run;
  float* dst = accum + (size_t)qidx * HD + (quad << 2);
  f32x4 oarr[4] = {o0, o1, o2, o3};
#pragma unroll
  for (int c = 0; c < 4; ++c)
#pragma unroll
    for (int u = 0; u < 4; ++u)
      atomicAdd(dst + (c << 4) + u, oarr[c][u] * inv);
}

// ---------------- K6: output projection (register-tiled GEMM)
__global__ __launch_bounds__(256) void outproj_kernel(
    const float* __restrict__ accum, const float* __restrict__ w_o,
    const float* __restrict__ b_o, float* __restrict__ out) {
  int sb = blockIdx.x & 31;
  int db = blockIdx.x >> 5;
  int tid = threadIdx.x;
  int tdx = tid & 31;
  int tsy = tid >> 5;

  __shared__ float  xs[GBS][GBK + 1];
  __shared__ float4 ws4[GBK * (GBD / 4)];

  float acc[4][4];
#pragma unroll
  for (int u = 0; u < 4; ++u)
#pragma unroll
    for (int c = 0; c < 4; ++c) acc[u][c] = 0.f;

  for (int kt = 0; kt < DM; kt += GBK) {
    __syncthreads();
    for (int e = tid; e < GBS * GBK; e += 256) {
      int s = e >> 5, k = e & 31;
      int kg = kt + k;
      int h = kg >> 6, dd = kg & 63;
      xs[s][k] = accum[((size_t)h * S + sb * GBS + s) * HD + dd] * 0.125f;
    }
    for (int e = tid; e < GBK * (GBD / 4); e += 256) {
      int k = e >> 5, d4 = e & 31;
      ws4[e] = ((const float4*)(w_o + (size_t)(kt + k) * DM + db * GBD))[d4];
    }
    __syncthreads();
#pragma unroll 8
    for (int kk = 0; kk < GBK; ++kk) {
      float4 b4 = ws4[kk * 32 + tdx];
      float bcol[4] = {b4.x, b4.y, b4.z, b4.w};
#pragma unroll
      for (int u = 0; u < 4; ++u) {
        float a = xs[tsy * 4 + u][kk];
#pragma unroll
        for (int c = 0; c < 4; ++c)
          acc[u][c] = fmaf(a, bcol[c], acc[u][c]);
      }
    }
  }
  int d0 = db * GBD + tdx * 4;
  float4 bb = *(const float4*)(b_o + d0);
  float bbv[4] = {bb.x, bb.y, bb.z, bb.w};
#pragma unroll
  for (int u = 0; u < 4; ++u) {
    int s = sb * GBS + tsy * 4 + u;
    float4 o = make_float4(acc[u][0] + bbv[0], acc[u][1] + bbv[1],
                           acc[u][2] + bbv[2], acc[u][3] + bbv[3]);
    *(float4*)(out + (size_t)s * DM + d0) = o;
  }
}

extern "C" void kernel_launch(void* const* d_in, const int* in_sizes, int n_in,
                              void* d_out, int out_size, void* d_ws, size_t ws_size,
                              hipStream_t stream) {
  const float* x    = (const float*)d_in[0];
  const float* w_qk = (const float*)d_in[1];
  const float* b_qk = (const float*)d_in[2];
  const float* w_v  = (const float*)d_in[3];
  const float* b_v  = (const float*)d_in[4];
  const float* w_o  = (const float*)d_in[5];
  const float* b_o  = (const float*)d_in[6];
  const float* rot  = (const float*)d_in[7];
  float* out = (float*)d_out;

  char* ws = (char*)d_ws;
  float* qkf   = (float*)(ws);                        // 2 MB
  float* vf    = (float*)(ws + 2u * 1024 * 1024);     // 2 MB
  float* accum = (float*)(ws + 4u * 1024 * 1024);     // 2 MB
  int* buckets = (int*)(ws + 6u * 1024 * 1024);       // 256 KB
  int* perm    = (int*)(ws + 6u * 1024 * 1024 + 256u * 1024);  // 256 KB
  int* counts  = (int*)(ws + 6u * 1024 * 1024 + 512u * 1024);  // 512 B
  int* offsets = counts + 128;
  int* cursor  = offsets + 128;

  hipMemsetAsync(counts, 0, 128 * sizeof(int), stream);
  hipMemsetAsync(accum, 0, (size_t)N * HD * sizeof(float), stream);

  proj2_kernel<<<256, 256, 0, stream>>>(x, w_qk, b_qk, w_v, b_v, qkf, vf);
  bucket_kernel<<<(NH * N) / 256, 256, 0, stream>>>(qkf, rot, buckets, counts);
  scan_kernel<<<1, 128, 0, stream>>>(counts, offsets, cursor);
  scatter_kernel<<<(NH * N) / 256, 256, 0, stream>>>(buckets, cursor, perm);
  attn_kernel<<<NH * 128, 256, 0, stream>>>(qkf, vf, perm, buckets, offsets, counts, accum);
  outproj_kernel<<<128, 256, 0, stream>>>(accum, w_o, b_o, out);
}